// Round 6
// baseline (741.558 us; speedup 1.0000x reference)
//
#include <hip/hip_runtime.h>
#include <hip/hip_cooperative_groups.h>
#include <math.h>

#define N_NODES 50000
#define N_EDGES 800000
#define OUTC 40
#define N_BATCH 10000
#define H2S 48   // padded stride for h2
#define NBLK 196 // ceil(50000/256)

typedef float f32x4 __attribute__((ext_vector_type(4)));
typedef short s16x8 __attribute__((ext_vector_type(8)));
typedef short s16x4 __attribute__((ext_vector_type(4)));

union Frag { s16x8 v; s16x4 h[2]; };

__device__ inline unsigned short f2bf(float f) {
    unsigned int u = __float_as_uint(f);
    u += 0x7fff + ((u >> 16) & 1);           // round-to-nearest-even
    return (unsigned short)(u >> 16);
}
__device__ inline void unpk8(uint4 u, float* f) {   // 8 packed bf16 -> 8 fp32
    f[0] = __uint_as_float(u.x << 16); f[1] = __uint_as_float(u.x & 0xffff0000u);
    f[2] = __uint_as_float(u.y << 16); f[3] = __uint_as_float(u.y & 0xffff0000u);
    f[4] = __uint_as_float(u.z << 16); f[5] = __uint_as_float(u.z & 0xffff0000u);
    f[6] = __uint_as_float(u.w << 16); f[7] = __uint_as_float(u.w & 0xffff0000u);
}

// ---------------- Cooperative CSR build + init (replaces 8 dispatches) ----------------
// phases: 0) zero cnt/norm1/stats + transpose W1  1) hist  2) hierarchical scan
//         (chunk scan -> bsum scan -> prefix + cur init)  3) scatter
__global__ __launch_bounds__(256) void csr_kernel(const int* __restrict__ ei,
                                                  const float* __restrict__ W1,
                                                  unsigned short* __restrict__ W1T,
                                                  int* __restrict__ cnt,
                                                  int* __restrict__ offs,
                                                  int* __restrict__ cur,
                                                  int* __restrict__ bsum,
                                                  int* __restrict__ bpre,
                                                  float* __restrict__ norm1,
                                                  float* __restrict__ stats,
                                                  int* __restrict__ srcs) {
    namespace cg = cooperative_groups;
    cg::grid_group grid = cg::this_grid();
    __shared__ int s[256];
    int t = threadIdx.x;
    int gid = blockIdx.x * 256 + t;
    int gstride = gridDim.x * 256;

    // phase 0
    for (int i = gid; i < N_NODES; i += gstride) { cnt[i] = 0; norm1[i] = 0.f; }
    for (int i = gid; i < 1024; i += gstride) stats[i] = 0.f;
    for (int i = gid; i < 65536; i += gstride) {
        int k = i >> 8, n = i & 255;
        W1T[n * 256 + k] = f2bf(W1[i]);
    }
    grid.sync();

    // phase 1: histogram of dst
    for (int e = gid; e < N_EDGES; e += gstride) atomicAdd(&cnt[ei[N_EDGES + e]], 1);
    grid.sync();

    // phase 2a: per-chunk exclusive scan (chunk = 256 nodes)
    for (int chunk = blockIdx.x; chunk < NBLK; chunk += gridDim.x) {
        int i = chunk * 256 + t;
        int v = (i < N_NODES) ? cnt[i] : 0;
        s[t] = v;
        __syncthreads();
        for (int off = 1; off < 256; off <<= 1) {
            int u = (t >= off) ? s[t - off] : 0;
            __syncthreads();
            s[t] += u;
            __syncthreads();
        }
        if (i < N_NODES) offs[i] = s[t] - v;   // exclusive within chunk
        if (t == 255) bsum[chunk] = s[255];
        __syncthreads();
    }
    grid.sync();

    // phase 2b: block 0 scans chunk sums
    if (blockIdx.x == 0) {
        int v = (t < NBLK) ? bsum[t] : 0;
        s[t] = v;
        __syncthreads();
        for (int off = 1; off < 256; off <<= 1) {
            int u = (t >= off) ? s[t - off] : 0;
            __syncthreads();
            s[t] += u;
            __syncthreads();
        }
        if (t < NBLK) bpre[t] = s[t] - v;      // exclusive
    }
    grid.sync();

    // phase 2c: global prefix; init running cursor
    for (int i = gid; i < N_NODES; i += gstride) {
        int o = offs[i] + bpre[i >> 8];
        offs[i] = o;
        cur[i] = o;
    }
    if (gid == 0) offs[N_NODES] = N_EDGES;
    grid.sync();

    // phase 3: scatter srcs into CSR order
    for (int e = gid; e < N_EDGES; e += gstride) {
        int d = ei[N_EDGES + e];
        int pos = atomicAdd(&cur[d], 1);
        srcs[pos] = ei[e];
    }
}

// ---------------- GEMM1 MFMA: h1 = bf16(feat @ W1 + b1) + row norms ----------------
#define LDA 40
__global__ __launch_bounds__(256) void gemm1_mfma(const float* __restrict__ A,
                                                  const unsigned short* __restrict__ BT,
                                                  const float* __restrict__ bias,
                                                  unsigned short* __restrict__ C,
                                                  float* __restrict__ norm1) {
    __shared__ unsigned short As[128 * LDA];
    __shared__ unsigned short Bs[128 * LDA];
    int t = threadIdx.x;
    int lane = t & 63, wave = t >> 6;
    int ln = lane & 15, quad = lane >> 4;
    int row0 = blockIdx.x * 128;
    int col0 = blockIdx.y * 128;
    int m0 = (wave & 1) * 64, n0 = (wave >> 1) * 64;
    f32x4 acc[4][4];
    #pragma unroll
    for (int i = 0; i < 4; i++)
        #pragma unroll
        for (int j = 0; j < 4; j++) acc[i][j] = (f32x4){0.f, 0.f, 0.f, 0.f};
    int r = t >> 1, half = t & 1;

    for (int k0 = 0; k0 < 256; k0 += 32) {
        {
            int gr = row0 + r;
            float4 v[4];
            if (gr < N_NODES) {
                const float4* src = (const float4*)(A + (size_t)gr * 256 + k0 + half * 16);
                v[0] = src[0]; v[1] = src[1]; v[2] = src[2]; v[3] = src[3];
            } else {
                float4 z = make_float4(0.f, 0.f, 0.f, 0.f);
                v[0] = z; v[1] = z; v[2] = z; v[3] = z;
            }
            ushort4* dst = (ushort4*)&As[r * LDA + half * 16];
            #pragma unroll
            for (int q = 0; q < 4; q++) {
                ushort4 u;
                u.x = f2bf(v[q].x); u.y = f2bf(v[q].y);
                u.z = f2bf(v[q].z); u.w = f2bf(v[q].w);
                dst[q] = u;
            }
        }
        {
            const ushort4* src = (const ushort4*)(BT + (size_t)(col0 + r) * 256 + k0 + half * 16);
            ushort4* dst = (ushort4*)&Bs[r * LDA + half * 16];
            dst[0] = src[0]; dst[1] = src[1]; dst[2] = src[2]; dst[3] = src[3];
        }
        __syncthreads();
        Frag af[4], bf[4];
        #pragma unroll
        for (int i = 0; i < 4; i++) {
            int ar = m0 + i * 16 + ln;
            af[i].h[0] = *(const s16x4*)&As[ar * LDA + quad * 8];
            af[i].h[1] = *(const s16x4*)&As[ar * LDA + quad * 8 + 4];
            int br = n0 + i * 16 + ln;
            bf[i].h[0] = *(const s16x4*)&Bs[br * LDA + quad * 8];
            bf[i].h[1] = *(const s16x4*)&Bs[br * LDA + quad * 8 + 4];
        }
        #pragma unroll
        for (int i = 0; i < 4; i++)
            #pragma unroll
            for (int j = 0; j < 4; j++)
                acc[i][j] = __builtin_amdgcn_mfma_f32_16x16x32_bf16(af[i].v, bf[j].v, acc[i][j], 0, 0, 0);
        __syncthreads();
    }
    // epilogue: D row = quad*4+reg, col = lane&15; accumulate bf16-rounded row norms
    float rn[4][4];
    #pragma unroll
    for (int i = 0; i < 4; i++)
        #pragma unroll
        for (int rg = 0; rg < 4; rg++) rn[i][rg] = 0.f;
    #pragma unroll
    for (int j = 0; j < 4; j++) {
        int gc = col0 + n0 + j * 16 + ln;
        float bv = bias[gc];
        #pragma unroll
        for (int i = 0; i < 4; i++) {
            int gb = row0 + m0 + i * 16 + quad * 4;
            #pragma unroll
            for (int rg = 0; rg < 4; rg++) {
                int gr = gb + rg;
                if (gr < N_NODES) {
                    unsigned short ub = f2bf(acc[i][j][rg] + bv);
                    C[(size_t)gr * 256 + gc] = ub;
                    float vb = __uint_as_float((unsigned int)ub << 16);
                    rn[i][rg] = fmaf(vb, vb, rn[i][rg]);
                }
            }
        }
    }
    #pragma unroll
    for (int i = 0; i < 4; i++)
        #pragma unroll
        for (int rg = 0; rg < 4; rg++) {
            float v = rn[i][rg];
            v += __shfl_xor(v, 1, 64);
            v += __shfl_xor(v, 2, 64);
            v += __shfl_xor(v, 4, 64);
            v += __shfl_xor(v, 8, 64);
            if (ln == 0) {
                int gr = row0 + m0 + i * 16 + quad * 4 + rg;
                if (gr < N_NODES) atomicAdd(&norm1[gr], v);
            }
        }
}

// ---------------- agg1: wave per node, 4 edge-slots x 16 lanes, 2 edges/slot/iter ----------------
// d2 = ||a||^2 + ||b||^2 - 2 a.b with precomputed norms (exact in fp32)
__global__ __launch_bounds__(256) void agg1_kernel(const unsigned short* __restrict__ h,
                                                   const float* __restrict__ norm1,
                                                   const int* __restrict__ offs,
                                                   const int* __restrict__ srcs,
                                                   const float* __restrict__ gamma_p,
                                                   float* __restrict__ x1) {
    int lane = threadIdx.x & 63;
    int node = blockIdx.x * 4 + (threadIdx.x >> 6);
    if (node >= N_NODES) return;
    int eslot = lane >> 4, cgrp = lane & 15;
    float g = gamma_p[0];
    float hd[16];
    {
        const uint4* hrow = (const uint4*)(h + (size_t)node * 256 + cgrp * 16);
        uint4 u0 = hrow[0], u1 = hrow[1];
        unpk8(u0, hd); unpk8(u1, hd + 8);
    }
    float nd = norm1[node];
    float acc[16];
    #pragma unroll
    for (int c = 0; c < 16; c++) acc[c] = 0.f;
    float den = 0.f;
    int beg = offs[node], end = offs[node + 1];
    int n_it = (end - beg + 7) >> 3;
    for (int it = 0; it < n_it; it++) {
        int i0 = beg + it * 8 + eslot;
        int i1 = i0 + 4;
        bool v0 = i0 < end, v1 = i1 < end;
        int s0 = v0 ? srcs[i0] : node;
        int s1 = v1 ? srcs[i1] : node;
        const uint4* r0 = (const uint4*)(h + (size_t)s0 * 256 + cgrp * 16);
        const uint4* r1 = (const uint4*)(h + (size_t)s1 * 256 + cgrp * 16);
        uint4 a0 = r0[0], a1 = r0[1];
        uint4 b0 = r1[0], b1 = r1[1];
        float ns0 = norm1[s0], ns1 = norm1[s1];
        float av0[16], av1[16];
        unpk8(a0, av0); unpk8(a1, av0 + 8);
        unpk8(b0, av1); unpk8(b1, av1 + 8);
        float dot0 = 0.f, dot1 = 0.f;
        #pragma unroll
        for (int c = 0; c < 16; c++) {
            dot0 = fmaf(av0[c], hd[c], dot0);
            dot1 = fmaf(av1[c], hd[c], dot1);
        }
        #pragma unroll
        for (int m = 1; m < 16; m <<= 1) {
            dot0 += __shfl_xor(dot0, m, 64);
            dot1 += __shfl_xor(dot1, m, 64);
        }
        float d20 = fmaf(-2.f, dot0, ns0 + nd);
        float d21 = fmaf(-2.f, dot1, ns1 + nd);
        float w0 = v0 ? __expf(-g * d20) : 0.f;
        float w1 = v1 ? __expf(-g * d21) : 0.f;
        den += w0 + w1;
        #pragma unroll
        for (int c = 0; c < 16; c++) {
            acc[c] = fmaf(w0, av0[c], acc[c]);
            acc[c] = fmaf(w1, av1[c], acc[c]);
        }
    }
    #pragma unroll
    for (int m = 16; m < 64; m <<= 1) {
        den += __shfl_xor(den, m, 64);
        #pragma unroll
        for (int c = 0; c < 16; c++) acc[c] += __shfl_xor(acc[c], m, 64);
    }
    if (eslot == 0) {
        float inv = 1.f / (den + 1e-16f);
        float4* out = (float4*)(x1 + (size_t)node * 256 + cgrp * 16);
        #pragma unroll
        for (int q = 0; q < 4; q++)
            out[q] = make_float4(acc[q * 4 + 0] * inv, acc[q * 4 + 1] * inv,
                                 acc[q * 4 + 2] * inv, acc[q * 4 + 3] * inv);
    }
}

// ---------------- per-channel stats, C=256 ----------------
__global__ __launch_bounds__(256) void stats1_kernel(const float* __restrict__ x,
                                                     float* __restrict__ sum,
                                                     float* __restrict__ sumsq) {
    int c = threadIdx.x;
    float s = 0.f, s2 = 0.f;
    for (int r = blockIdx.x; r < N_NODES; r += gridDim.x) {
        float v = x[(size_t)r * 256 + c];
        s += v;
        s2 += v * v;
    }
    atomicAdd(&sum[c], s);
    atomicAdd(&sumsq[c], s2);
}

// ---------------- GEMM2 + fused BN1/ReLU: h2(stride 48) = relu(bn(x1)) @ W2 + b2 ----------------
__global__ __launch_bounds__(256) void gemm2_kernel(const float* __restrict__ X,
                                                    const float* __restrict__ W2,
                                                    const float* __restrict__ bias,
                                                    const float* __restrict__ sum1,
                                                    const float* __restrict__ sumsq1,
                                                    const float* __restrict__ bg,
                                                    const float* __restrict__ bb,
                                                    float* __restrict__ H) {
    __shared__ float W2s[40 * 260];
    __shared__ float aas[256], bbs[256];
    int t = threadIdx.x;
    for (int c = 0; c < 40; c++) W2s[c * 260 + t] = W2[(size_t)t * 40 + c];
    {
        const float invN = 1.f / N_NODES;
        float mu = sum1[t] * invN;
        float var = sumsq1[t] * invN - mu * mu;
        float rs = rsqrtf(var + 1e-5f) * bg[t];
        aas[t] = rs;
        bbs[t] = bb[t] - mu * rs;
    }
    __syncthreads();
    int slot = t >> 2, cg = t & 3;
    int rbase = blockIdx.x * 256 + slot;
    const float4* xp[4];
    #pragma unroll
    for (int rr = 0; rr < 4; rr++) xp[rr] = (const float4*)(X + (size_t)(rbase + rr * 64) * 256);
    float acc[4][10];
    #pragma unroll
    for (int rr = 0; rr < 4; rr++)
        #pragma unroll
        for (int i = 0; i < 10; i++) acc[rr][i] = 0.f;

    for (int k4 = 0; k4 < 64; k4++) {
        int k = k4 * 4;
        float4 a4 = *(const float4*)&aas[k];
        float4 b4 = *(const float4*)&bbs[k];
        float4 w4[10];
        #pragma unroll
        for (int i = 0; i < 10; i++) w4[i] = *(const float4*)&W2s[(cg * 10 + i) * 260 + k];
        #pragma unroll
        for (int rr = 0; rr < 4; rr++) {
            float4 xv = xp[rr][k4];
            float y0 = fmaxf(fmaf(xv.x, a4.x, b4.x), 0.f);
            float y1 = fmaxf(fmaf(xv.y, a4.y, b4.y), 0.f);
            float y2 = fmaxf(fmaf(xv.z, a4.z, b4.z), 0.f);
            float y3 = fmaxf(fmaf(xv.w, a4.w, b4.w), 0.f);
            #pragma unroll
            for (int i = 0; i < 10; i++)
                acc[rr][i] += y0 * w4[i].x + y1 * w4[i].y + y2 * w4[i].z + y3 * w4[i].w;
        }
    }
    float4 z4 = make_float4(0.f, 0.f, 0.f, 0.f);
    #pragma unroll
    for (int rr = 0; rr < 4; rr++) {
        int row = rbase + rr * 64;
        if (row < N_NODES) {
            float* out = H + (size_t)row * H2S + cg * 10;
            #pragma unroll
            for (int i = 0; i < 10; i++) out[i] = acc[rr][i] + bias[cg * 10 + i];
            if (cg == 3) {   // zero the 8 pad columns (40..47)
                *(float4*)(H + (size_t)row * H2S + 40) = z4;
                *(float4*)(H + (size_t)row * H2S + 44) = z4;
            }
        }
    }
}

// ---------------- agg2: wave per node, 8 edge-slots x 8 lanes (h2 stride 48, pad=0) ----------------
__global__ __launch_bounds__(256) void agg2_kernel(const float* __restrict__ h,
                                                   const int* __restrict__ offs,
                                                   const int* __restrict__ srcs,
                                                   const float* __restrict__ gamma_p,
                                                   float* __restrict__ x2) {
    int lane = threadIdx.x & 63;
    int node = blockIdx.x * 4 + (threadIdx.x >> 6);
    if (node >= N_NODES) return;
    int eslot = lane >> 3, cgrp = lane & 7;
    float g = gamma_p[0];
    float hd[6];
    {
        const float2* hrow = (const float2*)(h + (size_t)node * H2S + cgrp * 6);
        float2 a = hrow[0], b = hrow[1], c = hrow[2];
        hd[0] = a.x; hd[1] = a.y; hd[2] = b.x; hd[3] = b.y; hd[4] = c.x; hd[5] = c.y;
    }
    float acc[6] = {0.f, 0.f, 0.f, 0.f, 0.f, 0.f};
    float den = 0.f;
    int beg = offs[node], end = offs[node + 1];
    int n_it = (end - beg + 7) >> 3;
    for (int it = 0; it < n_it; it++) {
        int i = beg + it * 8 + eslot;
        bool valid = i < end;
        int s = valid ? srcs[i] : node;
        const float2* arow = (const float2*)(h + (size_t)s * H2S + cgrp * 6);
        float2 a = arow[0], b = arow[1], c = arow[2];
        float av[6];
        av[0] = a.x; av[1] = a.y; av[2] = b.x; av[3] = b.y; av[4] = c.x; av[5] = c.y;
        float d2 = 0.f;
        #pragma unroll
        for (int j = 0; j < 6; j++) { float d = av[j] - hd[j]; d2 = fmaf(d, d, d2); }
        d2 += __shfl_xor(d2, 1, 64);
        d2 += __shfl_xor(d2, 2, 64);
        d2 += __shfl_xor(d2, 4, 64);
        float w = valid ? __expf(-g * d2) : 0.f;
        den += w;
        #pragma unroll
        for (int j = 0; j < 6; j++) acc[j] = fmaf(w, av[j], acc[j]);
    }
    #pragma unroll
    for (int m = 8; m < 64; m <<= 1) {
        den += __shfl_xor(den, m, 64);
        #pragma unroll
        for (int j = 0; j < 6; j++) acc[j] += __shfl_xor(acc[j], m, 64);
    }
    if (eslot == 0) {
        float inv = 1.f / (den + 1e-16f);
        int cb = cgrp * 6;
        #pragma unroll
        for (int j = 0; j < 6; j++)
            if (cb + j < OUTC) x2[(size_t)node * OUTC + cb + j] = acc[j] * inv;
    }
}

// ---------------- per-channel stats, C=40 ----------------
__global__ __launch_bounds__(256) void stats2_kernel(const float* __restrict__ x,
                                                     float* __restrict__ sum,
                                                     float* __restrict__ sumsq) {
    int c = threadIdx.x;
    if (c >= OUTC) return;
    float s = 0.f, s2 = 0.f;
    for (int r = blockIdx.x * 4 + threadIdx.y; r < N_NODES; r += gridDim.x * 4) {
        float v = x[(size_t)r * OUTC + c];
        s += v;
        s2 += v * v;
    }
    atomicAdd(&sum[c], s);
    atomicAdd(&sumsq[c], s2);
}

// ---------------- BN2 + ReLU + gather + log_softmax ----------------
__global__ __launch_bounds__(256) void final_kernel(const float* __restrict__ x2,
                                                    const float* __restrict__ sum,
                                                    const float* __restrict__ sumsq,
                                                    const float* __restrict__ g,
                                                    const float* __restrict__ b,
                                                    const int* __restrict__ batch,
                                                    float* __restrict__ out) {
    int lane = threadIdx.x & 63;
    int row = blockIdx.x * 4 + (threadIdx.x >> 6);
    if (row >= N_BATCH) return;
    int node = batch[row];
    bool act = lane < OUTC;
    float v = -INFINITY;
    if (act) {
        const float invN = 1.f / N_NODES;
        float mu = sum[lane] * invN;
        float var = sumsq[lane] * invN - mu * mu;
        float xv = x2[(size_t)node * OUTC + lane];
        float y = (xv - mu) * rsqrtf(var + 1e-5f) * g[lane] + b[lane];
        v = fmaxf(y, 0.f);
    }
    float m = v;
    #pragma unroll
    for (int s = 1; s < 64; s <<= 1) m = fmaxf(m, __shfl_xor(m, s, 64));
    float p = act ? expf(v - m) : 0.f;
    float ssum = p;
    #pragma unroll
    for (int s = 1; s < 64; s <<= 1) ssum += __shfl_xor(ssum, s, 64);
    if (act) out[(size_t)row * OUTC + lane] = v - m - logf(ssum);
}

extern "C" void kernel_launch(void* const* d_in, const int* in_sizes, int n_in,
                              void* d_out, int out_size, void* d_ws, size_t ws_size,
                              hipStream_t stream) {
    const float* feat   = (const float*)d_in[0];
    const int*   ei     = (const int*)d_in[1];
    const int*   batch  = (const int*)d_in[2];
    const float* W1     = (const float*)d_in[3];
    const float* b1     = (const float*)d_in[4];
    const float* gamma1 = (const float*)d_in[5];
    const float* W2     = (const float*)d_in[6];
    const float* b2     = (const float*)d_in[7];
    const float* gamma2 = (const float*)d_in[8];
    const float* bn1w   = (const float*)d_in[9];
    const float* bn1b   = (const float*)d_in[10];
    const float* bn2w   = (const float*)d_in[11];
    const float* bn2b   = (const float*)d_in[12];

    char* ws = (char*)d_ws;
    // layout (aliased by liveness):
    //   [0, 25.6MB)      h1 bf16 [50000,256]   (later h2 fp32 [50000,48] = 9.6MB)
    //   [25.6, 76.8MB)   x1 fp32 [50000,256]   (later x2 fp32 [50000,40])
    //   [76.8MB, +128KB) W1T bf16 [256,256]
    //   [77.0MB ..)      offs / cnt / cur / srcs / bsum / bpre / stats / norm1
    unsigned short* h1  = (unsigned short*)ws;
    float* x1           = (float*)(ws + 25600000);
    unsigned short* w1t = (unsigned short*)(ws + 76800000);
    int* offs           = (int*)(ws + 77000000);
    int* cnt            = (int*)(ws + 77200064);
    int* cur            = (int*)(ws + 77400128);
    int* srcs           = (int*)(ws + 77600192);
    int* bsum           = (int*)(ws + 80800256);
    int* bpre           = (int*)(ws + 80801280);
    float* stats        = (float*)(ws + 80802304);
    float* norm1        = (float*)(ws + 80806400);
    float* sum1   = stats;
    float* sumsq1 = stats + 256;
    float* sum2   = stats + 512;
    float* sumsq2 = stats + 576;
    float* h2 = (float*)ws;
    float* x2 = x1;
    float* out = (float*)d_out;

    // CSR build + all zero-init + W1 transpose in ONE cooperative kernel
    {
        const int* ei_l = ei; const float* W1_l = W1;
        void* args[] = {(void*)&ei_l, (void*)&W1_l, (void*)&w1t, (void*)&cnt,
                        (void*)&offs, (void*)&cur, (void*)&bsum, (void*)&bpre,
                        (void*)&norm1, (void*)&stats, (void*)&srcs};
        hipLaunchCooperativeKernel((const void*)csr_kernel, dim3(512), dim3(256),
                                   args, 0, stream);
    }

    // layer 1
    gemm1_mfma<<<dim3(391, 2), 256, 0, stream>>>(feat, w1t, b1, h1, norm1);
    agg1_kernel<<<(N_NODES + 3) / 4, 256, 0, stream>>>(h1, norm1, offs, srcs, gamma1, x1);
    stats1_kernel<<<512, 256, 0, stream>>>(x1, sum1, sumsq1);

    // layer 2 (BN1+ReLU fused into gemm2; gemm2 zeroes h2 pad cols itself)
    gemm2_kernel<<<196, 256, 0, stream>>>(x1, W2, b2, sum1, sumsq1, bn1w, bn1b, h2);
    agg2_kernel<<<(N_NODES + 3) / 4, 256, 0, stream>>>(h2, offs, srcs, gamma2, x2);
    stats2_kernel<<<512, dim3(64, 4), 0, stream>>>(x2, sum2, sumsq2);
    final_kernel<<<(N_BATCH + 3) / 4, 256, 0, stream>>>(x2, sum2, sumsq2, bn2w, bn2b, batch, out);
}

// Round 7
// 455.861 us; speedup vs baseline: 1.6267x; 1.6267x over previous
//
#include <hip/hip_runtime.h>
#include <math.h>

#define N_NODES 50000
#define N_EDGES 800000
#define OUTC 40
#define N_BATCH 10000
#define H2S 48   // padded stride for h2
#define NBLK 196 // ceil(50000/256)

typedef float f32x4 __attribute__((ext_vector_type(4)));
typedef short s16x8 __attribute__((ext_vector_type(8)));
typedef short s16x4 __attribute__((ext_vector_type(4)));

union Frag { s16x8 v; s16x4 h[2]; };

__device__ inline unsigned short f2bf(float f) {
    unsigned int u = __float_as_uint(f);
    u += 0x7fff + ((u >> 16) & 1);           // round-to-nearest-even
    return (unsigned short)(u >> 16);
}
__device__ inline void unpk8(uint4 u, float* f) {   // 8 packed bf16 -> 8 fp32
    f[0] = __uint_as_float(u.x << 16); f[1] = __uint_as_float(u.x & 0xffff0000u);
    f[2] = __uint_as_float(u.y << 16); f[3] = __uint_as_float(u.y & 0xffff0000u);
    f[4] = __uint_as_float(u.z << 16); f[5] = __uint_as_float(u.z & 0xffff0000u);
    f[6] = __uint_as_float(u.w << 16); f[7] = __uint_as_float(u.w & 0xffff0000u);
}

// ---------------- init: zero cnt/norm1/stats + transpose W1 -> bf16 W1T ----------------
// NOTE (R6 post-mortem): do NOT fuse CSR phases with grid.sync() — each
// cooperative grid barrier costs ~70 µs on MI355X; discrete launches are ~2 µs.
__global__ __launch_bounds__(256) void init_kernel(const float* __restrict__ W1,
                                                   unsigned short* __restrict__ W1T,
                                                   int* __restrict__ cnt,
                                                   float* __restrict__ norm1,
                                                   float* __restrict__ stats) {
    int gid = blockIdx.x * 256 + threadIdx.x;
    int gstride = gridDim.x * 256;
    for (int i = gid; i < N_NODES; i += gstride) { cnt[i] = 0; norm1[i] = 0.f; }
    for (int i = gid; i < 1024; i += gstride) stats[i] = 0.f;
    for (int i = gid; i < 65536; i += gstride) {
        int k = i >> 8, n = i & 255;
        W1T[n * 256 + k] = f2bf(W1[i]);
    }
}

// ---------------- CSR build ----------------
__global__ __launch_bounds__(256) void hist_kernel(const int* __restrict__ ei,
                                                   int* __restrict__ cnt) {
    int e = blockIdx.x * 256 + threadIdx.x;
    if (e < N_EDGES) atomicAdd(&cnt[ei[N_EDGES + e]], 1);
}

__global__ __launch_bounds__(256) void bsum_kernel(const int* __restrict__ cnt,
                                                   int* __restrict__ bsum) {
    __shared__ int s[256];
    int t = threadIdx.x;
    int i = blockIdx.x * 256 + t;
    s[t] = (i < N_NODES) ? cnt[i] : 0;
    __syncthreads();
    for (int off = 128; off > 0; off >>= 1) {
        if (t < off) s[t] += s[t + off];
        __syncthreads();
    }
    if (t == 0) bsum[blockIdx.x] = s[0];
}

__global__ __launch_bounds__(256) void bscan_kernel(const int* __restrict__ bsum,
                                                    int* __restrict__ bpre) {
    __shared__ int s[256];
    int t = threadIdx.x;
    s[t] = (t < NBLK) ? bsum[t] : 0;
    __syncthreads();
    for (int off = 1; off < 256; off <<= 1) {
        int v = (t >= off) ? s[t - off] : 0;
        __syncthreads();
        s[t] += v;
        __syncthreads();
    }
    if (t < NBLK) bpre[t] = (t > 0) ? s[t - 1] : 0;
}

// per-chunk scan + global prefix; also initializes the scatter cursor
__global__ __launch_bounds__(256) void blockscan_kernel(const int* __restrict__ cnt,
                                                        const int* __restrict__ bpre,
                                                        int* __restrict__ offs,
                                                        int* __restrict__ cur) {
    __shared__ int s[256];
    int t = threadIdx.x;
    int i = blockIdx.x * 256 + t;
    s[t] = (i < N_NODES) ? cnt[i] : 0;
    __syncthreads();
    for (int off = 1; off < 256; off <<= 1) {
        int v = (t >= off) ? s[t - off] : 0;
        __syncthreads();
        s[t] += v;
        __syncthreads();
    }
    int excl = (t > 0) ? s[t - 1] : 0;
    int base = bpre[blockIdx.x];
    if (i < N_NODES) { offs[i] = base + excl; cur[i] = base + excl; }
    if (i == 0) offs[N_NODES] = N_EDGES;
}

__global__ __launch_bounds__(256) void scatter_kernel(const int* __restrict__ ei,
                                                      int* __restrict__ cur,
                                                      int* __restrict__ srcs) {
    int e = blockIdx.x * 256 + threadIdx.x;
    if (e >= N_EDGES) return;
    int d = ei[N_EDGES + e];
    int pos = atomicAdd(&cur[d], 1);
    srcs[pos] = ei[e];
}

// ---------------- GEMM1 MFMA: h1 = bf16(feat @ W1 + b1) + row norms ----------------
#define LDA 40
__global__ __launch_bounds__(256) void gemm1_mfma(const float* __restrict__ A,
                                                  const unsigned short* __restrict__ BT,
                                                  const float* __restrict__ bias,
                                                  unsigned short* __restrict__ C,
                                                  float* __restrict__ norm1) {
    __shared__ unsigned short As[128 * LDA];
    __shared__ unsigned short Bs[128 * LDA];
    int t = threadIdx.x;
    int lane = t & 63, wave = t >> 6;
    int ln = lane & 15, quad = lane >> 4;
    int row0 = blockIdx.x * 128;
    int col0 = blockIdx.y * 128;
    int m0 = (wave & 1) * 64, n0 = (wave >> 1) * 64;
    f32x4 acc[4][4];
    #pragma unroll
    for (int i = 0; i < 4; i++)
        #pragma unroll
        for (int j = 0; j < 4; j++) acc[i][j] = (f32x4){0.f, 0.f, 0.f, 0.f};
    int r = t >> 1, half = t & 1;

    for (int k0 = 0; k0 < 256; k0 += 32) {
        {
            int gr = row0 + r;
            float4 v[4];
            if (gr < N_NODES) {
                const float4* src = (const float4*)(A + (size_t)gr * 256 + k0 + half * 16);
                v[0] = src[0]; v[1] = src[1]; v[2] = src[2]; v[3] = src[3];
            } else {
                float4 z = make_float4(0.f, 0.f, 0.f, 0.f);
                v[0] = z; v[1] = z; v[2] = z; v[3] = z;
            }
            ushort4* dst = (ushort4*)&As[r * LDA + half * 16];
            #pragma unroll
            for (int q = 0; q < 4; q++) {
                ushort4 u;
                u.x = f2bf(v[q].x); u.y = f2bf(v[q].y);
                u.z = f2bf(v[q].z); u.w = f2bf(v[q].w);
                dst[q] = u;
            }
        }
        {
            const ushort4* src = (const ushort4*)(BT + (size_t)(col0 + r) * 256 + k0 + half * 16);
            ushort4* dst = (ushort4*)&Bs[r * LDA + half * 16];
            dst[0] = src[0]; dst[1] = src[1]; dst[2] = src[2]; dst[3] = src[3];
        }
        __syncthreads();
        Frag af[4], bf[4];
        #pragma unroll
        for (int i = 0; i < 4; i++) {
            int ar = m0 + i * 16 + ln;
            af[i].h[0] = *(const s16x4*)&As[ar * LDA + quad * 8];
            af[i].h[1] = *(const s16x4*)&As[ar * LDA + quad * 8 + 4];
            int br = n0 + i * 16 + ln;
            bf[i].h[0] = *(const s16x4*)&Bs[br * LDA + quad * 8];
            bf[i].h[1] = *(const s16x4*)&Bs[br * LDA + quad * 8 + 4];
        }
        #pragma unroll
        for (int i = 0; i < 4; i++)
            #pragma unroll
            for (int j = 0; j < 4; j++)
                acc[i][j] = __builtin_amdgcn_mfma_f32_16x16x32_bf16(af[i].v, bf[j].v, acc[i][j], 0, 0, 0);
        __syncthreads();
    }
    // epilogue: D row = quad*4+reg, col = lane&15; accumulate bf16-rounded row norms
    float rn[4][4];
    #pragma unroll
    for (int i = 0; i < 4; i++)
        #pragma unroll
        for (int rg = 0; rg < 4; rg++) rn[i][rg] = 0.f;
    #pragma unroll
    for (int j = 0; j < 4; j++) {
        int gc = col0 + n0 + j * 16 + ln;
        float bv = bias[gc];
        #pragma unroll
        for (int i = 0; i < 4; i++) {
            int gb = row0 + m0 + i * 16 + quad * 4;
            #pragma unroll
            for (int rg = 0; rg < 4; rg++) {
                int gr = gb + rg;
                if (gr < N_NODES) {
                    unsigned short ub = f2bf(acc[i][j][rg] + bv);
                    C[(size_t)gr * 256 + gc] = ub;
                    float vb = __uint_as_float((unsigned int)ub << 16);
                    rn[i][rg] = fmaf(vb, vb, rn[i][rg]);
                }
            }
        }
    }
    #pragma unroll
    for (int i = 0; i < 4; i++)
        #pragma unroll
        for (int rg = 0; rg < 4; rg++) {
            float v = rn[i][rg];
            v += __shfl_xor(v, 1, 64);
            v += __shfl_xor(v, 2, 64);
            v += __shfl_xor(v, 4, 64);
            v += __shfl_xor(v, 8, 64);
            if (ln == 0) {
                int gr = row0 + m0 + i * 16 + quad * 4 + rg;
                if (gr < N_NODES) atomicAdd(&norm1[gr], v);
            }
        }
}

// ---------------- agg1: wave per node, 4 edge-slots x 16 lanes, 2 edges/slot/iter ----------------
// d2 = ||a||^2 + ||b||^2 - 2 a.b with precomputed norms (exact in fp32)
__global__ __launch_bounds__(256) void agg1_kernel(const unsigned short* __restrict__ h,
                                                   const float* __restrict__ norm1,
                                                   const int* __restrict__ offs,
                                                   const int* __restrict__ srcs,
                                                   const float* __restrict__ gamma_p,
                                                   float* __restrict__ x1) {
    int lane = threadIdx.x & 63;
    int node = blockIdx.x * 4 + (threadIdx.x >> 6);
    if (node >= N_NODES) return;
    int eslot = lane >> 4, cgrp = lane & 15;
    float g = gamma_p[0];
    float hd[16];
    {
        const uint4* hrow = (const uint4*)(h + (size_t)node * 256 + cgrp * 16);
        uint4 u0 = hrow[0], u1 = hrow[1];
        unpk8(u0, hd); unpk8(u1, hd + 8);
    }
    float nd = norm1[node];
    float acc[16];
    #pragma unroll
    for (int c = 0; c < 16; c++) acc[c] = 0.f;
    float den = 0.f;
    int beg = offs[node], end = offs[node + 1];
    int n_it = (end - beg + 7) >> 3;
    for (int it = 0; it < n_it; it++) {
        int i0 = beg + it * 8 + eslot;
        int i1 = i0 + 4;
        bool v0 = i0 < end, v1 = i1 < end;
        int s0 = v0 ? srcs[i0] : node;
        int s1 = v1 ? srcs[i1] : node;
        const uint4* r0 = (const uint4*)(h + (size_t)s0 * 256 + cgrp * 16);
        const uint4* r1 = (const uint4*)(h + (size_t)s1 * 256 + cgrp * 16);
        uint4 a0 = r0[0], a1 = r0[1];
        uint4 b0 = r1[0], b1 = r1[1];
        float ns0 = norm1[s0], ns1 = norm1[s1];
        float av0[16], av1[16];
        unpk8(a0, av0); unpk8(a1, av0 + 8);
        unpk8(b0, av1); unpk8(b1, av1 + 8);
        float dot0 = 0.f, dot1 = 0.f;
        #pragma unroll
        for (int c = 0; c < 16; c++) {
            dot0 = fmaf(av0[c], hd[c], dot0);
            dot1 = fmaf(av1[c], hd[c], dot1);
        }
        #pragma unroll
        for (int m = 1; m < 16; m <<= 1) {
            dot0 += __shfl_xor(dot0, m, 64);
            dot1 += __shfl_xor(dot1, m, 64);
        }
        float d20 = fmaf(-2.f, dot0, ns0 + nd);
        float d21 = fmaf(-2.f, dot1, ns1 + nd);
        float w0 = v0 ? __expf(-g * d20) : 0.f;
        float w1 = v1 ? __expf(-g * d21) : 0.f;
        den += w0 + w1;
        #pragma unroll
        for (int c = 0; c < 16; c++) {
            acc[c] = fmaf(w0, av0[c], acc[c]);
            acc[c] = fmaf(w1, av1[c], acc[c]);
        }
    }
    #pragma unroll
    for (int m = 16; m < 64; m <<= 1) {
        den += __shfl_xor(den, m, 64);
        #pragma unroll
        for (int c = 0; c < 16; c++) acc[c] += __shfl_xor(acc[c], m, 64);
    }
    if (eslot == 0) {
        float inv = 1.f / (den + 1e-16f);
        float4* out = (float4*)(x1 + (size_t)node * 256 + cgrp * 16);
        #pragma unroll
        for (int q = 0; q < 4; q++)
            out[q] = make_float4(acc[q * 4 + 0] * inv, acc[q * 4 + 1] * inv,
                                 acc[q * 4 + 2] * inv, acc[q * 4 + 3] * inv);
    }
}

// ---------------- per-channel stats, C=256 ----------------
__global__ __launch_bounds__(256) void stats1_kernel(const float* __restrict__ x,
                                                     float* __restrict__ sum,
                                                     float* __restrict__ sumsq) {
    int c = threadIdx.x;
    float s = 0.f, s2 = 0.f;
    for (int r = blockIdx.x; r < N_NODES; r += gridDim.x) {
        float v = x[(size_t)r * 256 + c];
        s += v;
        s2 += v * v;
    }
    atomicAdd(&sum[c], s);
    atomicAdd(&sumsq[c], s2);
}

// ---------------- GEMM2 + fused BN1/ReLU: h2(stride 48) = relu(bn(x1)) @ W2 + b2 ----------------
__global__ __launch_bounds__(256) void gemm2_kernel(const float* __restrict__ X,
                                                    const float* __restrict__ W2,
                                                    const float* __restrict__ bias,
                                                    const float* __restrict__ sum1,
                                                    const float* __restrict__ sumsq1,
                                                    const float* __restrict__ bg,
                                                    const float* __restrict__ bb,
                                                    float* __restrict__ H) {
    __shared__ float W2s[40 * 260];
    __shared__ float aas[256], bbs[256];
    int t = threadIdx.x;
    for (int c = 0; c < 40; c++) W2s[c * 260 + t] = W2[(size_t)t * 40 + c];
    {
        const float invN = 1.f / N_NODES;
        float mu = sum1[t] * invN;
        float var = sumsq1[t] * invN - mu * mu;
        float rs = rsqrtf(var + 1e-5f) * bg[t];
        aas[t] = rs;
        bbs[t] = bb[t] - mu * rs;
    }
    __syncthreads();
    int slot = t >> 2, cg = t & 3;
    int rbase = blockIdx.x * 256 + slot;
    const float4* xp[4];
    #pragma unroll
    for (int rr = 0; rr < 4; rr++) xp[rr] = (const float4*)(X + (size_t)(rbase + rr * 64) * 256);
    float acc[4][10];
    #pragma unroll
    for (int rr = 0; rr < 4; rr++)
        #pragma unroll
        for (int i = 0; i < 10; i++) acc[rr][i] = 0.f;

    for (int k4 = 0; k4 < 64; k4++) {
        int k = k4 * 4;
        float4 a4 = *(const float4*)&aas[k];
        float4 b4 = *(const float4*)&bbs[k];
        float4 w4[10];
        #pragma unroll
        for (int i = 0; i < 10; i++) w4[i] = *(const float4*)&W2s[(cg * 10 + i) * 260 + k];
        #pragma unroll
        for (int rr = 0; rr < 4; rr++) {
            float4 xv = xp[rr][k4];
            float y0 = fmaxf(fmaf(xv.x, a4.x, b4.x), 0.f);
            float y1 = fmaxf(fmaf(xv.y, a4.y, b4.y), 0.f);
            float y2 = fmaxf(fmaf(xv.z, a4.z, b4.z), 0.f);
            float y3 = fmaxf(fmaf(xv.w, a4.w, b4.w), 0.f);
            #pragma unroll
            for (int i = 0; i < 10; i++)
                acc[rr][i] += y0 * w4[i].x + y1 * w4[i].y + y2 * w4[i].z + y3 * w4[i].w;
        }
    }
    float4 z4 = make_float4(0.f, 0.f, 0.f, 0.f);
    #pragma unroll
    for (int rr = 0; rr < 4; rr++) {
        int row = rbase + rr * 64;
        if (row < N_NODES) {
            float* out = H + (size_t)row * H2S + cg * 10;
            #pragma unroll
            for (int i = 0; i < 10; i++) out[i] = acc[rr][i] + bias[cg * 10 + i];
            if (cg == 3) {   // zero the 8 pad columns (40..47)
                *(float4*)(H + (size_t)row * H2S + 40) = z4;
                *(float4*)(H + (size_t)row * H2S + 44) = z4;
            }
        }
    }
}

// ---------------- agg2: wave per node, 8 edge-slots x 8 lanes (h2 stride 48, pad=0) ----------------
__global__ __launch_bounds__(256) void agg2_kernel(const float* __restrict__ h,
                                                   const int* __restrict__ offs,
                                                   const int* __restrict__ srcs,
                                                   const float* __restrict__ gamma_p,
                                                   float* __restrict__ x2) {
    int lane = threadIdx.x & 63;
    int node = blockIdx.x * 4 + (threadIdx.x >> 6);
    if (node >= N_NODES) return;
    int eslot = lane >> 3, cgrp = lane & 7;
    float g = gamma_p[0];
    float hd[6];
    {
        const float2* hrow = (const float2*)(h + (size_t)node * H2S + cgrp * 6);
        float2 a = hrow[0], b = hrow[1], c = hrow[2];
        hd[0] = a.x; hd[1] = a.y; hd[2] = b.x; hd[3] = b.y; hd[4] = c.x; hd[5] = c.y;
    }
    float acc[6] = {0.f, 0.f, 0.f, 0.f, 0.f, 0.f};
    float den = 0.f;
    int beg = offs[node], end = offs[node + 1];
    int n_it = (end - beg + 7) >> 3;
    for (int it = 0; it < n_it; it++) {
        int i = beg + it * 8 + eslot;
        bool valid = i < end;
        int s = valid ? srcs[i] : node;
        const float2* arow = (const float2*)(h + (size_t)s * H2S + cgrp * 6);
        float2 a = arow[0], b = arow[1], c = arow[2];
        float av[6];
        av[0] = a.x; av[1] = a.y; av[2] = b.x; av[3] = b.y; av[4] = c.x; av[5] = c.y;
        float d2 = 0.f;
        #pragma unroll
        for (int j = 0; j < 6; j++) { float d = av[j] - hd[j]; d2 = fmaf(d, d, d2); }
        d2 += __shfl_xor(d2, 1, 64);
        d2 += __shfl_xor(d2, 2, 64);
        d2 += __shfl_xor(d2, 4, 64);
        float w = valid ? __expf(-g * d2) : 0.f;
        den += w;
        #pragma unroll
        for (int j = 0; j < 6; j++) acc[j] = fmaf(w, av[j], acc[j]);
    }
    #pragma unroll
    for (int m = 8; m < 64; m <<= 1) {
        den += __shfl_xor(den, m, 64);
        #pragma unroll
        for (int j = 0; j < 6; j++) acc[j] += __shfl_xor(acc[j], m, 64);
    }
    if (eslot == 0) {
        float inv = 1.f / (den + 1e-16f);
        int cb = cgrp * 6;
        #pragma unroll
        for (int j = 0; j < 6; j++)
            if (cb + j < OUTC) x2[(size_t)node * OUTC + cb + j] = acc[j] * inv;
    }
}

// ---------------- per-channel stats, C=40 ----------------
__global__ __launch_bounds__(256) void stats2_kernel(const float* __restrict__ x,
                                                     float* __restrict__ sum,
                                                     float* __restrict__ sumsq) {
    int c = threadIdx.x;
    if (c >= OUTC) return;
    float s = 0.f, s2 = 0.f;
    for (int r = blockIdx.x * 4 + threadIdx.y; r < N_NODES; r += gridDim.x * 4) {
        float v = x[(size_t)r * OUTC + c];
        s += v;
        s2 += v * v;
    }
    atomicAdd(&sum[c], s);
    atomicAdd(&sumsq[c], s2);
}

// ---------------- BN2 + ReLU + gather + log_softmax ----------------
__global__ __launch_bounds__(256) void final_kernel(const float* __restrict__ x2,
                                                    const float* __restrict__ sum,
                                                    const float* __restrict__ sumsq,
                                                    const float* __restrict__ g,
                                                    const float* __restrict__ b,
                                                    const int* __restrict__ batch,
                                                    float* __restrict__ out) {
    int lane = threadIdx.x & 63;
    int row = blockIdx.x * 4 + (threadIdx.x >> 6);
    if (row >= N_BATCH) return;
    int node = batch[row];
    bool act = lane < OUTC;
    float v = -INFINITY;
    if (act) {
        const float invN = 1.f / N_NODES;
        float mu = sum[lane] * invN;
        float var = sumsq[lane] * invN - mu * mu;
        float xv = x2[(size_t)node * OUTC + lane];
        float y = (xv - mu) * rsqrtf(var + 1e-5f) * g[lane] + b[lane];
        v = fmaxf(y, 0.f);
    }
    float m = v;
    #pragma unroll
    for (int s = 1; s < 64; s <<= 1) m = fmaxf(m, __shfl_xor(m, s, 64));
    float p = act ? expf(v - m) : 0.f;
    float ssum = p;
    #pragma unroll
    for (int s = 1; s < 64; s <<= 1) ssum += __shfl_xor(ssum, s, 64);
    if (act) out[(size_t)row * OUTC + lane] = v - m - logf(ssum);
}

extern "C" void kernel_launch(void* const* d_in, const int* in_sizes, int n_in,
                              void* d_out, int out_size, void* d_ws, size_t ws_size,
                              hipStream_t stream) {
    const float* feat   = (const float*)d_in[0];
    const int*   ei     = (const int*)d_in[1];
    const int*   batch  = (const int*)d_in[2];
    const float* W1     = (const float*)d_in[3];
    const float* b1     = (const float*)d_in[4];
    const float* gamma1 = (const float*)d_in[5];
    const float* W2     = (const float*)d_in[6];
    const float* b2     = (const float*)d_in[7];
    const float* gamma2 = (const float*)d_in[8];
    const float* bn1w   = (const float*)d_in[9];
    const float* bn1b   = (const float*)d_in[10];
    const float* bn2w   = (const float*)d_in[11];
    const float* bn2b   = (const float*)d_in[12];

    char* ws = (char*)d_ws;
    // layout (aliased by liveness):
    //   [0, 25.6MB)      h1 bf16 [50000,256]   (later h2 fp32 [50000,48] = 9.6MB)
    //   [25.6, 76.8MB)   x1 fp32 [50000,256]   (later x2 fp32 [50000,40])
    //   [76.8MB, +128KB) W1T bf16 [256,256]
    //   [77.0MB ..)      offs / cnt / cur / srcs / bsum / bpre / stats / norm1
    unsigned short* h1  = (unsigned short*)ws;
    float* x1           = (float*)(ws + 25600000);
    unsigned short* w1t = (unsigned short*)(ws + 76800000);
    int* offs           = (int*)(ws + 77000000);
    int* cnt            = (int*)(ws + 77200064);
    int* cur            = (int*)(ws + 77400128);
    int* srcs           = (int*)(ws + 77600192);
    int* bsum           = (int*)(ws + 80800256);
    int* bpre           = (int*)(ws + 80801280);
    float* stats        = (float*)(ws + 80802304);
    float* norm1        = (float*)(ws + 80806400);
    float* sum1   = stats;
    float* sumsq1 = stats + 256;
    float* sum2   = stats + 512;
    float* sumsq2 = stats + 576;
    float* h2 = (float*)ws;
    float* x2 = x1;
    float* out = (float*)d_out;

    // init + CSR build (discrete kernels — no cooperative grid.sync, see R6 note)
    init_kernel<<<256, 256, 0, stream>>>(W1, w1t, cnt, norm1, stats);
    hist_kernel<<<(N_EDGES + 255) / 256, 256, 0, stream>>>(ei, cnt);
    bsum_kernel<<<NBLK, 256, 0, stream>>>(cnt, bsum);
    bscan_kernel<<<1, 256, 0, stream>>>(bsum, bpre);
    blockscan_kernel<<<NBLK, 256, 0, stream>>>(cnt, bpre, offs, cur);
    scatter_kernel<<<(N_EDGES + 255) / 256, 256, 0, stream>>>(ei, cur, srcs);

    // layer 1
    gemm1_mfma<<<dim3(391, 2), 256, 0, stream>>>(feat, w1t, b1, h1, norm1);
    agg1_kernel<<<(N_NODES + 3) / 4, 256, 0, stream>>>(h1, norm1, offs, srcs, gamma1, x1);
    stats1_kernel<<<512, 256, 0, stream>>>(x1, sum1, sumsq1);

    // layer 2 (BN1+ReLU fused into gemm2; gemm2 zeroes h2 pad cols itself)
    gemm2_kernel<<<196, 256, 0, stream>>>(x1, W2, b2, sum1, sumsq1, bn1w, bn1b, h2);
    agg2_kernel<<<(N_NODES + 3) / 4, 256, 0, stream>>>(h2, offs, srcs, gamma2, x2);
    stats2_kernel<<<512, dim3(64, 4), 0, stream>>>(x2, sum2, sumsq2);
    final_kernel<<<(N_BATCH + 3) / 4, 256, 0, stream>>>(x2, sum2, sumsq2, bn2w, bn2b, batch, out);
}